// Round 4
// baseline (376.846 us; speedup 1.0000x reference)
//
#include <hip/hip_runtime.h>

#define BATCH 2048
#define NF 512
#define FD 64
#define BT 16                 // batch rows per block
#define SLOTF (16 * 17 * 4)   // floats per LDS slot: [kq=16][b=16+1pad][4]

// One block = (output o, batch tile of 16 rows). Entire 15-node subtree in
// one block; intermediates live in LDS only. Single buffer of 8 slots with
// slot reuse across stages:
//   stage1: waves 0..7 -> slots 0..7 (H staged in own slot, then C overwrites)
//   stage2: reads 0..7 (k-loop) | sync | stores nodes 0..3 -> slots 0..3 | sync
//   stage3: reads 0..3, stores nodes 0..1 -> slots 4..5 (dead) | sync
//   stage4: reads 4..5 -> global
// LDS = 8*SLOTF*4 + 128 B = 34.9 KB -> 4 blocks/CU; with launch_bounds(512,8)
// (<=64 VGPR) the 1024-block grid is a single full-occupancy pass.
__global__ __launch_bounds__(512, 8) void fused_dag_kernel(
    const float* __restrict__ in_graph,
    const float* __restrict__ weights,
    const int* __restrict__ fold_idx,
    const int* __restrict__ out_idx,
    float* __restrict__ out) {
  __shared__ float bufA[8 * SLOTF];
  __shared__ int T[32];  // 0:F4 | 1..2:F3 | 3..6:F2 | 7..14:F1 | 15..30:F0

  const int o    = blockIdx.x & 7;
  const int tile = blockIdx.x >> 3;
  const int B0   = tile * BT;
  const int t    = threadIdx.x;

  // ---- per-block fold-table rebuild (5 dependent levels, L2-hot) ----
  if (t == 0) {
    int f4 = out_idx[o];
    T[0] = f4;
    T[1] = fold_idx[(3 * NF + f4) * 2 + 0];
    T[2] = fold_idx[(3 * NF + f4) * 2 + 1];
    #pragma unroll
    for (int i = 0; i < 2; ++i) {
      int f = T[1 + i];
      T[3 + 2 * i]     = fold_idx[(2 * NF + f) * 2 + 0];
      T[3 + 2 * i + 1] = fold_idx[(2 * NF + f) * 2 + 1];
    }
    #pragma unroll
    for (int i = 0; i < 4; ++i) {
      int f = T[3 + i];
      T[7 + 2 * i]     = fold_idx[(1 * NF + f) * 2 + 0];
      T[7 + 2 * i + 1] = fold_idx[(1 * NF + f) * 2 + 1];
    }
    #pragma unroll
    for (int i = 0; i < 8; ++i) {
      int f = T[7 + i];
      T[15 + 2 * i]     = fold_idx[(0 * NF + f) * 2 + 0];
      T[15 + 2 * i + 1] = fold_idx[(0 * NF + f) * 2 + 1];
    }
  }
  __syncthreads();

  const int w  = t >> 6;    // wave 0..7
  const int l  = t & 63;
  const int tx = l & 15;    // j-quad (cols 4*tx..+3)
  const int ty = l >> 4;    // 0..3

  // ================= stage 1: 8 nodes, 1 wave each =================
  {
    float* slot = bufA + w * SLOTF;
    const int f0 = T[15 + 2 * w];
    const int f1 = T[16 + 2 * w];
    // H = x[f0] (.) x[f1] staged into own slot (same-wave scratch, no barrier)
    #pragma unroll
    for (int r = 0; r < 4; ++r) {
      const int b = ty * 4 + r;
      const float* row = in_graph + (size_t)(B0 + b) * NF * FD + tx * 4;
      float4 a = *(const float4*)(row + f0 * FD);
      float4 c = *(const float4*)(row + f1 * FD);
      float4 h;
      h.x = a.x * c.x; h.y = a.y * c.y; h.z = a.z * c.z; h.w = a.w * c.w;
      *(float4*)(slot + (tx * 17 + b) * 4) = h;
    }
    const float* W = weights + (size_t)(0 * NF + T[7 + w]) * (FD * FD);
    float4 acc[4];
    #pragma unroll
    for (int r = 0; r < 4; ++r) acc[r] = make_float4(0.f, 0.f, 0.f, 0.f);
    #pragma unroll 1
    for (int kq = 0; kq < 16; ++kq) {
      const float* Wk = W + kq * 4 * FD + tx * 4;
      float4 w0 = *(const float4*)(Wk);
      float4 w1 = *(const float4*)(Wk + FD);
      float4 w2 = *(const float4*)(Wk + 2 * FD);
      float4 w3 = *(const float4*)(Wk + 3 * FD);
      #pragma unroll
      for (int r = 0; r < 4; ++r) {
        float4 h = *(const float4*)(slot + (kq * 17 + 4 * r + ty) * 4);
        acc[r].x = fmaf(h.x, w0.x, acc[r].x); acc[r].y = fmaf(h.x, w0.y, acc[r].y);
        acc[r].z = fmaf(h.x, w0.z, acc[r].z); acc[r].w = fmaf(h.x, w0.w, acc[r].w);
        acc[r].x = fmaf(h.y, w1.x, acc[r].x); acc[r].y = fmaf(h.y, w1.y, acc[r].y);
        acc[r].z = fmaf(h.y, w1.z, acc[r].z); acc[r].w = fmaf(h.y, w1.w, acc[r].w);
        acc[r].x = fmaf(h.z, w2.x, acc[r].x); acc[r].y = fmaf(h.z, w2.y, acc[r].y);
        acc[r].z = fmaf(h.z, w2.z, acc[r].z); acc[r].w = fmaf(h.z, w2.w, acc[r].w);
        acc[r].x = fmaf(h.w, w3.x, acc[r].x); acc[r].y = fmaf(h.w, w3.y, acc[r].y);
        acc[r].z = fmaf(h.w, w3.z, acc[r].z); acc[r].w = fmaf(h.w, w3.w, acc[r].w);
      }
    }
    #pragma unroll
    for (int r = 0; r < 4; ++r)
      *(float4*)(slot + (tx * 17 + 4 * r + ty) * 4) = acc[r];
  }
  __syncthreads();   // sync1: stage-1 outputs visible

  // ================= stage 2: 4 nodes, 2 waves each =================
  {
    const int node = w >> 1, half = w & 1;
    const float* P0 = bufA + (2 * node) * SLOTF;
    const float* P1 = bufA + (2 * node + 1) * SLOTF;
    const float* W = weights + (size_t)(1 * NF + T[3 + node]) * (FD * FD);
    float4 acc[2];
    acc[0] = make_float4(0.f, 0.f, 0.f, 0.f);
    acc[1] = make_float4(0.f, 0.f, 0.f, 0.f);
    #pragma unroll 1
    for (int kq = 0; kq < 16; ++kq) {
      const float* Wk = W + kq * 4 * FD + tx * 4;
      float4 w0 = *(const float4*)(Wk);
      float4 w1 = *(const float4*)(Wk + FD);
      float4 w2 = *(const float4*)(Wk + 2 * FD);
      float4 w3 = *(const float4*)(Wk + 3 * FD);
      #pragma unroll
      for (int r = 0; r < 2; ++r) {
        const int b = half * 8 + 4 * r + ty;
        float4 pa = *(const float4*)(P0 + (kq * 17 + b) * 4);
        float4 pb = *(const float4*)(P1 + (kq * 17 + b) * 4);
        float4 h;
        h.x = pa.x * pb.x; h.y = pa.y * pb.y; h.z = pa.z * pb.z; h.w = pa.w * pb.w;
        acc[r].x = fmaf(h.x, w0.x, acc[r].x); acc[r].y = fmaf(h.x, w0.y, acc[r].y);
        acc[r].z = fmaf(h.x, w0.z, acc[r].z); acc[r].w = fmaf(h.x, w0.w, acc[r].w);
        acc[r].x = fmaf(h.y, w1.x, acc[r].x); acc[r].y = fmaf(h.y, w1.y, acc[r].y);
        acc[r].z = fmaf(h.y, w1.z, acc[r].z); acc[r].w = fmaf(h.y, w1.w, acc[r].w);
        acc[r].x = fmaf(h.z, w2.x, acc[r].x); acc[r].y = fmaf(h.z, w2.y, acc[r].y);
        acc[r].z = fmaf(h.z, w2.z, acc[r].z); acc[r].w = fmaf(h.z, w2.w, acc[r].w);
        acc[r].x = fmaf(h.w, w3.x, acc[r].x); acc[r].y = fmaf(h.w, w3.y, acc[r].y);
        acc[r].z = fmaf(h.w, w3.z, acc[r].z); acc[r].w = fmaf(h.w, w3.w, acc[r].w);
      }
    }
    __syncthreads();  // sync2: all stage-2 reads of slots 0..7 complete
    float* slot = bufA + node * SLOTF;  // reuse dead slots 0..3
    #pragma unroll
    for (int r = 0; r < 2; ++r)
      *(float4*)(slot + (tx * 17 + half * 8 + 4 * r + ty) * 4) = acc[r];
  }
  __syncthreads();   // sync3: stage-2 outputs visible

  // ================= stage 3: 2 nodes, 4 waves each =================
  {
    const int node = w >> 2, q = w & 3;
    const float* P0 = bufA + (2 * node) * SLOTF;
    const float* P1 = bufA + (2 * node + 1) * SLOTF;
    const float* W = weights + (size_t)(2 * NF + T[1 + node]) * (FD * FD);
    const int b = q * 4 + ty;
    float4 acc = make_float4(0.f, 0.f, 0.f, 0.f);
    #pragma unroll 1
    for (int kq = 0; kq < 16; ++kq) {
      const float* Wk = W + kq * 4 * FD + tx * 4;
      float4 w0 = *(const float4*)(Wk);
      float4 w1 = *(const float4*)(Wk + FD);
      float4 w2 = *(const float4*)(Wk + 2 * FD);
      float4 w3 = *(const float4*)(Wk + 3 * FD);
      float4 pa = *(const float4*)(P0 + (kq * 17 + b) * 4);
      float4 pb = *(const float4*)(P1 + (kq * 17 + b) * 4);
      float4 h;
      h.x = pa.x * pb.x; h.y = pa.y * pb.y; h.z = pa.z * pb.z; h.w = pa.w * pb.w;
      acc.x = fmaf(h.x, w0.x, acc.x); acc.y = fmaf(h.x, w0.y, acc.y);
      acc.z = fmaf(h.x, w0.z, acc.z); acc.w = fmaf(h.x, w0.w, acc.w);
      acc.x = fmaf(h.y, w1.x, acc.x); acc.y = fmaf(h.y, w1.y, acc.y);
      acc.z = fmaf(h.y, w1.z, acc.z); acc.w = fmaf(h.y, w1.w, acc.w);
      acc.x = fmaf(h.z, w2.x, acc.x); acc.y = fmaf(h.z, w2.y, acc.y);
      acc.z = fmaf(h.z, w2.z, acc.z); acc.w = fmaf(h.z, w2.w, acc.w);
      acc.x = fmaf(h.w, w3.x, acc.x); acc.y = fmaf(h.w, w3.y, acc.y);
      acc.z = fmaf(h.w, w3.z, acc.z); acc.w = fmaf(h.w, w3.w, acc.w);
    }
    // store into slots 4..5 (dead since sync2); no pre-store barrier needed:
    // stage-3 reads touch only slots 0..3.
    float* slot = bufA + (4 + node) * SLOTF;
    *(float4*)(slot + (tx * 17 + b) * 4) = acc;
  }
  __syncthreads();   // sync4: stage-3 outputs visible

  // ================= stage 4: 1 node, waves 0..3 =================
  if (w < 4) {
    const float* P0 = bufA + 4 * SLOTF;
    const float* P1 = bufA + 5 * SLOTF;
    const float* W = weights + (size_t)(3 * NF + T[0]) * (FD * FD);
    const int b = w * 4 + ty;
    float4 acc = make_float4(0.f, 0.f, 0.f, 0.f);
    #pragma unroll 1
    for (int kq = 0; kq < 16; ++kq) {
      const float* Wk = W + kq * 4 * FD + tx * 4;
      float4 w0 = *(const float4*)(Wk);
      float4 w1 = *(const float4*)(Wk + FD);
      float4 w2 = *(const float4*)(Wk + 2 * FD);
      float4 w3 = *(const float4*)(Wk + 3 * FD);
      float4 pa = *(const float4*)(P0 + (kq * 17 + b) * 4);
      float4 pb = *(const float4*)(P1 + (kq * 17 + b) * 4);
      float4 h;
      h.x = pa.x * pb.x; h.y = pa.y * pb.y; h.z = pa.z * pb.z; h.w = pa.w * pb.w;
      acc.x = fmaf(h.x, w0.x, acc.x); acc.y = fmaf(h.x, w0.y, acc.y);
      acc.z = fmaf(h.x, w0.z, acc.z); acc.w = fmaf(h.x, w0.w, acc.w);
      acc.x = fmaf(h.y, w1.x, acc.x); acc.y = fmaf(h.y, w1.y, acc.y);
      acc.z = fmaf(h.y, w1.z, acc.z); acc.w = fmaf(h.y, w1.w, acc.w);
      acc.x = fmaf(h.z, w2.x, acc.x); acc.y = fmaf(h.z, w2.y, acc.y);
      acc.z = fmaf(h.z, w2.z, acc.z); acc.w = fmaf(h.z, w2.w, acc.w);
      acc.x = fmaf(h.w, w3.x, acc.x); acc.y = fmaf(h.w, w3.y, acc.y);
      acc.z = fmaf(h.w, w3.z, acc.z); acc.w = fmaf(h.w, w3.w, acc.w);
    }
    // out[b][o][j], fp32
    *(float4*)(out + ((size_t)(B0 + b) * 8 + o) * FD + tx * 4) = acc;
  }
}

extern "C" void kernel_launch(void* const* d_in, const int* in_sizes, int n_in,
                              void* d_out, int out_size, void* d_ws, size_t ws_size,
                              hipStream_t stream) {
  const float* in_graph = (const float*)d_in[0];
  const float* weights  = (const float*)d_in[1];
  const int*   fold_idx = (const int*)d_in[2];
  const int*   out_idx  = (const int*)d_in[3];
  float* out = (float*)d_out;

  // grid: 8 outputs x 128 batch tiles of 16 rows = 1024 blocks
  //     = 256 CUs x 4 blocks/CU -> single full-occupancy pass. d_ws unused.
  fused_dag_kernel<<<(BATCH / BT) * 8, 512, 0, stream>>>(
      in_graph, weights, fold_idx, out_idx, out);
}